// Round 2
// baseline (85880.450 us; speedup 1.0000x reference)
//
#include <hip/hip_runtime.h>
#include <math.h>

#define T_STEPS 8192
#define I_DIM   64
#define H_DIM   2048
#define O_DIM   128
#define NBLK    256     // one block per CU; each owns 8 h-indices (32 gate rows)
#define NTHR    512     // 8 waves

// ws layout: float Hbuf[2][2048] | unsigned flags[256]
#define WS_HBUF_FLOATS (2 * H_DIM)

__device__ __forceinline__ float sigmoid_f(float x) {
    return 1.0f / (1.0f + __expf(-x));
}

__global__ void init_ws_kernel(float* Hbuf, unsigned int* flags) {
    int tid = blockIdx.x * blockDim.x + threadIdx.x;
    if (tid < WS_HBUF_FLOATS) Hbuf[tid] = 0.0f;
    if (tid < NBLK) flags[tid] = 0u;
}

// Persistent LSTM recurrence. One block per CU.
// Wave w (0..7): gate q = w>>1, h-sub-offset joff = (w&1)*4; rows = q*2048 + cu*8 + joff + i, i=0..3
// Lane covers k = kk*64 + lane, kk = 0..31  (conflict-free LDS, coalesced weight loads)
__global__ __launch_bounds__(NTHR, 2) void lstm_persistent(
    const float* __restrict__ x,     // [T, 64]
    const float* __restrict__ Wih,   // [8192, 64]
    const float* __restrict__ Whh,   // [8192, 2048]
    const float* __restrict__ bih,   // [8192]
    const float* __restrict__ bhh,   // [8192]
    float* __restrict__ Hbuf,        // [2][2048] in ws
    unsigned int* __restrict__ flags)// [256] in ws
{
    const int cu   = blockIdx.x;
    const int tid  = threadIdx.x;
    const int w    = tid >> 6;
    const int lane = tid & 63;

    __shared__ float hbuf[H_DIM];   // 8 KB
    __shared__ float xbuf[I_DIM];
    __shared__ float gbuf[32];      // gbuf[g*8 + j] = pre-activation of gate g, h-sub j

    const int q    = w >> 1;
    const int joff = (w & 1) * 4;
    const int row0 = q * H_DIM + cu * 8 + joff;

    // ---- one-time: load W_hh fragment into registers ----
    float wreg[4][32];
#pragma unroll
    for (int i = 0; i < 4; i++) {
        const float* p = Whh + (size_t)(row0 + i) * H_DIM + lane;
#pragma unroll
        for (int kk = 0; kk < 32; kk++)
            wreg[i][kk] = p[kk * 64];
    }
    // x-part: lane handles row (row0 + (lane>>4)), k-range (lane&15)*4 .. +4
    float xw[4];
    {
        const int xr = row0 + (lane >> 4);
        const float* p = Wih + (size_t)xr * I_DIM + (lane & 15) * 4;
#pragma unroll
        for (int m = 0; m < 4; m++) xw[m] = p[m];
    }
    // biases for elementwise phase (wave 0, lanes 0..7), h-index = cu*8 + lane
    float bias[4] = {0.f, 0.f, 0.f, 0.f};
    if (w == 0 && lane < 8) {
#pragma unroll
        for (int g = 0; g < 4; g++) {
            int r = g * H_DIM + cu * 8 + lane;
            bias[g] = bih[r] + bhh[r];
        }
    }
    float cstate = 0.0f;

    for (int t = 0; t < T_STEPS; t++) {
        // ---- 1. wave 0 waits until all CUs posted step t's h ----
        if (w == 0) {
            const unsigned int tgt = (unsigned int)t;
            for (;;) {
                unsigned int mn = 0xFFFFFFFFu;
#pragma unroll
                for (int m = 0; m < 4; m++) {
                    unsigned int f = __hip_atomic_load(&flags[lane * 4 + m],
                                                       __ATOMIC_RELAXED, __HIP_MEMORY_SCOPE_AGENT);
                    if (f < mn) mn = f;
                }
                if (__all(mn >= tgt)) break;
            }
            __builtin_amdgcn_fence(__ATOMIC_ACQUIRE, "agent");
        }
        __syncthreads();

        // ---- 2. stage h (and x_t) into LDS ----
        {
            float* Hc = Hbuf + (t & 1) * H_DIM;
#pragma unroll
            for (int m = 0; m < 4; m++) {
                int idx = tid + m * NTHR;  // consecutive lanes -> consecutive dwords
                hbuf[idx] = __hip_atomic_load(&Hc[idx], __ATOMIC_RELAXED, __HIP_MEMORY_SCOPE_AGENT);
            }
            if (tid < I_DIM) xbuf[tid] = x[(size_t)t * I_DIM + tid];
        }
        __syncthreads();

        // ---- 3. dot products: 4 rows per wave ----
        float acc0 = 0.f, acc1 = 0.f, acc2 = 0.f, acc3 = 0.f;
#pragma unroll
        for (int kk = 0; kk < 32; kk++) {
            float hv = hbuf[kk * 64 + lane];
            acc0 += wreg[0][kk] * hv;
            acc1 += wreg[1][kk] * hv;
            acc2 += wreg[2][kk] * hv;
            acc3 += wreg[3][kk] * hv;
        }
        // fold in W_ih * x_t
        {
            float xp = 0.f;
            const int b = (lane & 15) * 4;
#pragma unroll
            for (int m = 0; m < 4; m++) xp += xw[m] * xbuf[b + m];
            const int sel = lane >> 4;
            acc0 += (sel == 0) ? xp : 0.0f;
            acc1 += (sel == 1) ? xp : 0.0f;
            acc2 += (sel == 2) ? xp : 0.0f;
            acc3 += (sel == 3) ? xp : 0.0f;
        }
        // wave-level butterfly reduction
#pragma unroll
        for (int off = 32; off; off >>= 1) {
            acc0 += __shfl_xor(acc0, off, 64);
            acc1 += __shfl_xor(acc1, off, 64);
            acc2 += __shfl_xor(acc2, off, 64);
            acc3 += __shfl_xor(acc3, off, 64);
        }
        if (lane == 0) {
            gbuf[q * 8 + joff + 0] = acc0;
            gbuf[q * 8 + joff + 1] = acc1;
            gbuf[q * 8 + joff + 2] = acc2;
            gbuf[q * 8 + joff + 3] = acc3;
        }
        __syncthreads();

        // ---- 4. elementwise cell update (wave 0, lanes 0..7) + publish ----
        if (w == 0 && lane < 8) {
            float gi = gbuf[0 * 8 + lane] + bias[0];
            float gf = gbuf[1 * 8 + lane] + bias[1];
            float gg = gbuf[2 * 8 + lane] + bias[2];
            float go = gbuf[3 * 8 + lane] + bias[3];
            float iv = sigmoid_f(gi);
            float fv = sigmoid_f(gf);
            float gv = tanhf(gg);
            float ov = sigmoid_f(go);
            cstate = fv * cstate + iv * gv;
            float hval = ov * tanhf(cstate);
            float* Hn = Hbuf + ((t + 1) & 1) * H_DIM;
            __hip_atomic_store(&Hn[cu * 8 + lane], hval,
                               __ATOMIC_RELAXED, __HIP_MEMORY_SCOPE_AGENT);
        }
        if (tid == 0) {
            __hip_atomic_store(&flags[cu], (unsigned int)(t + 1),
                               __ATOMIC_RELEASE, __HIP_MEMORY_SCOPE_AGENT);
        }
    }
}

// Final linear: out[o] = h_T . W_lin[o,:] + b_lin[o].  One wave per output.
__global__ void final_linear(const float* __restrict__ hT,
                             const float* __restrict__ Wlin,
                             const float* __restrict__ blin,
                             float* __restrict__ out)
{
    int gw   = (blockIdx.x * blockDim.x + threadIdx.x) >> 6;
    int lane = threadIdx.x & 63;
    if (gw < O_DIM) {
        const float* wp = Wlin + (size_t)gw * H_DIM;
        float s = 0.f;
        for (int k = lane; k < H_DIM; k += 64)
            s += wp[k] * hT[k];
#pragma unroll
        for (int off = 32; off; off >>= 1) s += __shfl_xor(s, off, 64);
        if (lane == 0) out[gw] = s + blin[gw];
    }
}

extern "C" void kernel_launch(void* const* d_in, const int* in_sizes, int n_in,
                              void* d_out, int out_size, void* d_ws, size_t ws_size,
                              hipStream_t stream)
{
    const float* x    = (const float*)d_in[0];
    const float* Wih  = (const float*)d_in[1];
    const float* Whh  = (const float*)d_in[2];
    const float* bih  = (const float*)d_in[3];
    const float* bhh  = (const float*)d_in[4];
    const float* Wlin = (const float*)d_in[5];
    const float* blin = (const float*)d_in[6];
    float* out = (float*)d_out;

    float* Hbuf = (float*)d_ws;
    unsigned int* flags = (unsigned int*)((char*)d_ws + WS_HBUF_FLOATS * sizeof(float));

    hipLaunchKernelGGL(init_ws_kernel, dim3(16), dim3(256), 0, stream, Hbuf, flags);

    void* args[] = { (void*)&x, (void*)&Wih, (void*)&Whh, (void*)&bih, (void*)&bhh,
                     (void*)&Hbuf, (void*)&flags };
    hipLaunchCooperativeKernel(reinterpret_cast<void*>(lstm_persistent),
                               dim3(NBLK), dim3(NTHR), args, 0, stream);

    // h_T ends up in Hbuf[0] (T even: step 8191 writes buffer (8191+1)&1 = 0)
    hipLaunchKernelGGL(final_linear, dim3(32), dim3(256), 0, stream,
                       Hbuf, Wlin, blin, out);
}

// Round 3
// 24864.899 us; speedup vs baseline: 3.4539x; 3.4539x over previous
//
#include <hip/hip_runtime.h>
#include <math.h>

#define T_STEPS 8192
#define I_DIM   64
#define H_DIM   2048
#define O_DIM   128
#define NBLK    256     // one block per CU; each owns 8 h-indices (32 gate rows)
#define NTHR    512     // 8 waves
#define NSLOT   4       // h slot ring depth
#define NAN_BITS 0x7FC00000u

// ws layout: float Hbuf[NSLOT][2048]
__device__ __forceinline__ float sigmoid_f(float x) {
    return 1.0f / (1.0f + __expf(-x));
}

__global__ void init_ws_kernel(unsigned int* Hbits) {
    int tid = blockIdx.x * blockDim.x + threadIdx.x;
    if (tid < NSLOT * H_DIM) {
        // slot 0 = h_0 = 0.0f; slots 1..3 = NaN sentinel ("not ready")
        Hbits[tid] = (tid < H_DIM) ? 0u : NAN_BITS;
    }
}

// Persistent LSTM recurrence. One block per CU. No fences, no flags:
// h data doubles as the ready signal (NaN sentinel = not ready).
// Wave w (0..7): gate q = w>>1, joff = (w&1)*4; rows = q*2048 + cu*8 + joff + i
// Lane covers k = kk*64 + lane (conflict-free LDS, coalesced weight loads)
__global__ __launch_bounds__(NTHR, 2) void lstm_persistent(
    const float* __restrict__ x,     // [T, 64]
    const float* __restrict__ Wih,   // [8192, 64]
    const float* __restrict__ Whh,   // [8192, 2048]
    const float* __restrict__ bih,   // [8192]
    const float* __restrict__ bhh,   // [8192]
    unsigned int* __restrict__ Hbits)// [NSLOT][2048] in ws (float bits)
{
    const int cu   = blockIdx.x;
    const int tid  = threadIdx.x;
    const int w    = tid >> 6;
    const int lane = tid & 63;

    __shared__ float hbuf[H_DIM];   // 8 KB
    __shared__ float xbuf[I_DIM];
    __shared__ float gbuf[32];      // gbuf[g*8 + j] = pre-activation of gate g, h-sub j

    const int q    = w >> 1;
    const int joff = (w & 1) * 4;
    const int row0 = q * H_DIM + cu * 8 + joff;

    // ---- one-time: W_hh fragment into registers ----
    float wreg[4][32];
#pragma unroll
    for (int i = 0; i < 4; i++) {
        const float* p = Whh + (size_t)(row0 + i) * H_DIM + lane;
#pragma unroll
        for (int kk = 0; kk < 32; kk++)
            wreg[i][kk] = p[kk * 64];
    }
    // x-part: lane handles row (row0 + (lane>>4)), k-range (lane&15)*4 .. +4
    float xw[4];
    {
        const int xr = row0 + (lane >> 4);
        const float* p = Wih + (size_t)xr * I_DIM + (lane & 15) * 4;
#pragma unroll
        for (int m = 0; m < 4; m++) xw[m] = p[m];
    }
    // biases: every wave keeps them (elementwise phase is replicated per wave)
    float bias[4] = {0.f, 0.f, 0.f, 0.f};
    if (lane < 8) {
#pragma unroll
        for (int g = 0; g < 4; g++) {
            int r = g * H_DIM + cu * 8 + lane;
            bias[g] = bih[r] + bhh[r];
        }
    }
    float cstate = 0.0f;   // replicated in lanes 0..7 of every wave

    for (int t = 0; t < T_STEPS; t++) {
        const int slot_r = t & (NSLOT - 1);
        const int slot_w = (t + 1) & (NSLOT - 1);
        const int slot_z = (t + 2) & (NSLOT - 1);

        // ---- 1. poll h_t (data-as-flag) and stage into LDS ----
        {
            const unsigned int* Hr = Hbits + slot_r * H_DIM;
            unsigned int u0, u1, u2, u3;
            do {
                u0 = __hip_atomic_load(Hr + tid,             __ATOMIC_RELAXED, __HIP_MEMORY_SCOPE_AGENT);
                u1 = __hip_atomic_load(Hr + tid + 1 * NTHR,  __ATOMIC_RELAXED, __HIP_MEMORY_SCOPE_AGENT);
                u2 = __hip_atomic_load(Hr + tid + 2 * NTHR,  __ATOMIC_RELAXED, __HIP_MEMORY_SCOPE_AGENT);
                u3 = __hip_atomic_load(Hr + tid + 3 * NTHR,  __ATOMIC_RELAXED, __HIP_MEMORY_SCOPE_AGENT);
            } while ((u0 == NAN_BITS) | (u1 == NAN_BITS) |
                     (u2 == NAN_BITS) | (u3 == NAN_BITS));
            hbuf[tid]            = __uint_as_float(u0);
            hbuf[tid + 1 * NTHR] = __uint_as_float(u1);
            hbuf[tid + 2 * NTHR] = __uint_as_float(u2);
            hbuf[tid + 3 * NTHR] = __uint_as_float(u3);
            if (tid < I_DIM) xbuf[tid] = x[(size_t)t * I_DIM + tid];
        }
        // reset own chunk 2 slots ahead (holds h_{t-2}, fully consumed by skew<=1).
        // __syncthreads' vmcnt(0) drain orders this before next iter's publish.
        if (w == 0 && lane < 8) {
            __hip_atomic_store(Hbits + slot_z * H_DIM + cu * 8 + lane, NAN_BITS,
                               __ATOMIC_RELAXED, __HIP_MEMORY_SCOPE_AGENT);
        }
        __syncthreads();

        // ---- 2. dot products: 4 rows per wave ----
        float acc0 = 0.f, acc1 = 0.f, acc2 = 0.f, acc3 = 0.f;
#pragma unroll
        for (int kk = 0; kk < 32; kk++) {
            float hv = hbuf[kk * 64 + lane];
            acc0 += wreg[0][kk] * hv;
            acc1 += wreg[1][kk] * hv;
            acc2 += wreg[2][kk] * hv;
            acc3 += wreg[3][kk] * hv;
        }
        {   // fold in W_ih * x_t
            float xp = 0.f;
            const int b = (lane & 15) * 4;
#pragma unroll
            for (int m = 0; m < 4; m++) xp += xw[m] * xbuf[b + m];
            const int sel = lane >> 4;
            acc0 += (sel == 0) ? xp : 0.0f;
            acc1 += (sel == 1) ? xp : 0.0f;
            acc2 += (sel == 2) ? xp : 0.0f;
            acc3 += (sel == 3) ? xp : 0.0f;
        }
#pragma unroll
        for (int off = 32; off; off >>= 1) {
            acc0 += __shfl_xor(acc0, off, 64);
            acc1 += __shfl_xor(acc1, off, 64);
            acc2 += __shfl_xor(acc2, off, 64);
            acc3 += __shfl_xor(acc3, off, 64);
        }
        if (lane == 0) {
            gbuf[q * 8 + joff + 0] = acc0;
            gbuf[q * 8 + joff + 1] = acc1;
            gbuf[q * 8 + joff + 2] = acc2;
            gbuf[q * 8 + joff + 3] = acc3;
        }
        __syncthreads();

        // ---- 3. elementwise cell update, replicated in every wave (lanes 0..7);
        //         wave 0 publishes (store IS the ready flag) ----
        if (lane < 8) {
            float gi = gbuf[0 * 8 + lane] + bias[0];
            float gf = gbuf[1 * 8 + lane] + bias[1];
            float gg = gbuf[2 * 8 + lane] + bias[2];
            float go = gbuf[3 * 8 + lane] + bias[3];
            float iv = sigmoid_f(gi);
            float fv = sigmoid_f(gf);
            float gv = tanhf(gg);
            float ov = sigmoid_f(go);
            cstate = fv * cstate + iv * gv;
            float hval = ov * tanhf(cstate);
            if (w == 0) {
                __hip_atomic_store(Hbits + slot_w * H_DIM + cu * 8 + lane,
                                   __float_as_uint(hval),
                                   __ATOMIC_RELAXED, __HIP_MEMORY_SCOPE_AGENT);
            }
        }
        // next iteration's poll phase touches only Hbits/hbuf/xbuf; gbuf reuse
        // is protected by the next iteration's first __syncthreads.
    }
}

// Final linear: out[o] = h_T . W_lin[o,:] + b_lin[o].  One wave per output.
// h_T lives in slot (T & 3) == 0.
__global__ void final_linear(const float* __restrict__ hT,
                             const float* __restrict__ Wlin,
                             const float* __restrict__ blin,
                             float* __restrict__ out)
{
    int gw   = (blockIdx.x * blockDim.x + threadIdx.x) >> 6;
    int lane = threadIdx.x & 63;
    if (gw < O_DIM) {
        const float* wp = Wlin + (size_t)gw * H_DIM;
        float s = 0.f;
        for (int k = lane; k < H_DIM; k += 64)
            s += wp[k] * hT[k];
#pragma unroll
        for (int off = 32; off; off >>= 1) s += __shfl_xor(s, off, 64);
        if (lane == 0) out[gw] = s + blin[gw];
    }
}

extern "C" void kernel_launch(void* const* d_in, const int* in_sizes, int n_in,
                              void* d_out, int out_size, void* d_ws, size_t ws_size,
                              hipStream_t stream)
{
    const float* x    = (const float*)d_in[0];
    const float* Wih  = (const float*)d_in[1];
    const float* Whh  = (const float*)d_in[2];
    const float* bih  = (const float*)d_in[3];
    const float* bhh  = (const float*)d_in[4];
    const float* Wlin = (const float*)d_in[5];
    const float* blin = (const float*)d_in[6];
    float* out = (float*)d_out;

    unsigned int* Hbits = (unsigned int*)d_ws;

    hipLaunchKernelGGL(init_ws_kernel, dim3((NSLOT * H_DIM + 255) / 256), dim3(256),
                       0, stream, Hbits);

    void* args[] = { (void*)&x, (void*)&Wih, (void*)&Whh, (void*)&bih, (void*)&bhh,
                     (void*)&Hbits };
    hipLaunchCooperativeKernel(reinterpret_cast<void*>(lstm_persistent),
                               dim3(NBLK), dim3(NTHR), args, 0, stream);

    // h_T is in slot (T_STEPS & 3) == 0
    hipLaunchKernelGGL(final_linear, dim3(32), dim3(256), 0, stream,
                       (const float*)Hbits, Wlin, blin, out);
}